// Round 10
// baseline (174.872 us; speedup 1.0000x reference)
//
#include <hip/hip_runtime.h>
#include <hip/hip_bf16.h>
#include <stdint.h>

typedef __attribute__((ext_vector_type(8))) short short8;
typedef __attribute__((ext_vector_type(4))) float f32x4;

#define NROWS  8192
#define DDIM   256
#define HHEADS 4
#define KTOT   1024            // H * D
#define BM     256
#define BN     256
#define BK     64
#define NT     (KTOT / BK)     // 16 K-tiles
#define NTB    (NROWS / BM)    // 32 tile rows
#define NOFF   (NTB * (NTB - 1) / 2)   // 496 strict-lower tiles
#define NTILES (NOFF + NTB)            // 528 jobs: off-diag first, diag last
#define NPERS  256                     // persistent blocks (1 per CU)

#define SBAR()  __builtin_amdgcn_s_barrier()
#define LGKM0() do { asm volatile("s_waitcnt lgkmcnt(0)" ::: "memory"); \
                     __builtin_amdgcn_sched_barrier(0); } while (0)
#define VMCNT(n) do { asm volatile("s_waitcnt vmcnt(" #n ")" ::: "memory"); \
                      __builtin_amdgcn_sched_barrier(0); } while (0)

__device__ __forceinline__ unsigned short f2bf(float f) {
  union { float f; uint32_t u; } v;
  v.f = f;
  uint32_t u = v.u;
  uint32_t r = (u + 0x7fffu + ((u >> 16) & 1u)) >> 16;
  return (unsigned short)r;
}

// --------------------------------------------------------------------------
// Kernel 1: Y[n, h*256+d] = bf16-normalized per-head scaled rows
// --------------------------------------------------------------------------
__global__ __launch_bounds__(256) void prep_y(const float* __restrict__ x,
                                              const float* __restrict__ av,
                                              unsigned short* __restrict__ Y) {
  __shared__ float a_sh[HHEADS][DDIM];
  __shared__ float red[4][HHEADS];

  const int t = threadIdx.x;
  #pragma unroll
  for (int h = 0; h < HHEADS; ++h) a_sh[h][t] = av[h * DDIM + t];
  __syncthreads();

  const int n = blockIdx.x;
  const float xd = x[(size_t)n * DDIM + t];

  float p[HHEADS], s[HHEADS];
  #pragma unroll
  for (int h = 0; h < HHEADS; ++h) { p[h] = a_sh[h][t] * xd; s[h] = p[h] * p[h]; }

  #pragma unroll
  for (int off = 32; off > 0; off >>= 1) {
    #pragma unroll
    for (int h = 0; h < HHEADS; ++h) s[h] += __shfl_xor(s[h], off, 64);
  }

  const int wave = t >> 6, lane = t & 63;
  if (lane == 0) {
    #pragma unroll
    for (int h = 0; h < HHEADS; ++h) red[wave][h] = s[h];
  }
  __syncthreads();

  #pragma unroll
  for (int h = 0; h < HHEADS; ++h) {
    const float sum = red[0][h] + red[1][h] + red[2][h] + red[3][h];
    const float rn = rsqrtf(fmaxf(sum, 1e-12f));
    Y[(size_t)n * KTOT + h * DDIM + t] = f2bf(p[h] * rn);
  }
}

// --------------------------------------------------------------------------
// stage one 128x64 bf16 half-tile: 2 x global_load_lds(16B) per thread.
// Linear LDS dest + inverse-swizzled global source (rule #21).
// --------------------------------------------------------------------------
__device__ __forceinline__ void stage_half(const unsigned short* __restrict__ Y,
                                           unsigned short* lds_region,
                                           int grow0, int k0, int tid) {
  #pragma unroll
  for (int i = 0; i < 2; ++i) {
    const int s    = i * 512 + tid;       // 16B slot 0..1023
    const int srow = s >> 3;              // 0..127
    const int gsl  = (s & 7) ^ (srow & 7);
    const unsigned short* gsrc =
        Y + (size_t)(grow0 + srow) * KTOT + k0 + gsl * 8;
    __builtin_amdgcn_global_load_lds(
        (const __attribute__((address_space(1))) void*)gsrc,
        (__attribute__((address_space(3))) void*)(lds_region + s * 8), 16, 0, 0);
  }
}

// --------------------------------------------------------------------------
// One 256x256 output tile: prologue + 8-phase K-loop + epilogue.
// Ledger (group computing tile T, phases a-d = quadrants 0-3):
//   a: issue A-lo(T+1)->buf[T+1]; b: A-hi(T+1)->buf[T+1]
//   c: B-lo(T+2)->buf[T];        d: B-hi(T+2)->buf[T]; vmcnt(4)
// Plain C stores (round-9 lesson: nontemporal stores cost +16 us).
// --------------------------------------------------------------------------
__device__ __forceinline__ void run_tile(const unsigned short* __restrict__ Y,
                                         float* __restrict__ C,
                                         unsigned short* lds,
                                         int by, int bx,
                                         int tid, int lane, int wr, int wn,
                                         int l15, int lh) {
  const int rowA0 = by * BM;
  const int rowB0 = bx * BN;

  const int arow = wr * 128 + l15;   // local A row base
  const int brow = wn * 64 + l15;    // local B row base
  const int slA0 = (0 + lh) ^ (arow & 7), slA1 = (4 + lh) ^ (arow & 7);
  const int slB0 = (0 + lh) ^ (brow & 7), slB1 = (4 + lh) ^ (brow & 7);

  f32x4 acc[8][4];
  #pragma unroll
  for (int m = 0; m < 8; ++m)
    #pragma unroll
    for (int n = 0; n < 4; ++n) acc[m][n] = (f32x4){0.f, 0.f, 0.f, 0.f};

  // prologue: K0 all 4 halves + B halves of K1
  stage_half(Y, lds + 0,             rowA0,       0,  tid);  // A-lo(0)
  stage_half(Y, lds + 8192,          rowA0 + 128, 0,  tid);  // A-hi(0)
  stage_half(Y, lds + 16384,         rowB0,       0,  tid);  // B-lo(0)
  stage_half(Y, lds + 24576,         rowB0 + 128, 0,  tid);  // B-hi(0)
  stage_half(Y, lds + 32768 + 16384, rowB0,       64, tid);  // B-lo(1)
  stage_half(Y, lds + 32768 + 24576, rowB0 + 128, 64, tid);  // B-hi(1)
  VMCNT(4);   // K0 complete; B(1) may fly
  SBAR();

  short8 bf[4][2], af[2][2];

#define READ_A(q) do {                                                        \
    _Pragma("unroll")                                                         \
    for (int mm = 0; mm < 2; ++mm) {                                          \
      const int r_ = arow + ((q) * 2 + mm) * 16;                              \
      af[mm][0] = *(const short8*)(lds + cur + r_ * 64 + slA0 * 8);           \
      af[mm][1] = *(const short8*)(lds + cur + r_ * 64 + slA1 * 8);           \
    }                                                                         \
  } while (0)

#define MFMA_QUAD(q) do {                                                     \
    __builtin_amdgcn_s_setprio(1);                                            \
    _Pragma("unroll")                                                         \
    for (int mm = 0; mm < 2; ++mm)                                            \
      _Pragma("unroll")                                                       \
      for (int n = 0; n < 4; ++n) {                                           \
        acc[(q)*2+mm][n] = __builtin_amdgcn_mfma_f32_16x16x32_bf16(           \
            af[mm][0], bf[n][0], acc[(q)*2+mm][n], 0, 0, 0);                  \
        acc[(q)*2+mm][n] = __builtin_amdgcn_mfma_f32_16x16x32_bf16(           \
            af[mm][1], bf[n][1], acc[(q)*2+mm][n], 0, 0, 0);                  \
      }                                                                       \
    __builtin_amdgcn_s_setprio(0);                                            \
  } while (0)

  for (int T = 0; T < NT; ++T) {
    const int cur = (T & 1) << 15;
    const int nxt = ((T + 1) & 1) << 15;
    const int k1  = (T + 1) * BK;
    const int k2  = (T + 2) * BK;

    // ---- phase a (quadrant 0): B frags + A m0,m1 ----
    if (T + 1 < NT) stage_half(Y, lds + nxt, rowA0, k1, tid);        // A-lo(T+1)
    #pragma unroll
    for (int n = 0; n < 4; ++n) {
      const int r_ = brow + n * 16;
      bf[n][0] = *(const short8*)(lds + cur + 16384 + r_ * 64 + slB0 * 8);
      bf[n][1] = *(const short8*)(lds + cur + 16384 + r_ * 64 + slB1 * 8);
    }
    READ_A(0);
    __builtin_amdgcn_sched_barrier(0);
    SBAR(); LGKM0();
    MFMA_QUAD(0);
    __builtin_amdgcn_sched_barrier(0);
    SBAR();

    // ---- phase b (quadrant 1) ----
    if (T + 1 < NT) stage_half(Y, lds + nxt + 8192, rowA0 + 128, k1, tid);
    READ_A(1);
    __builtin_amdgcn_sched_barrier(0);
    SBAR(); LGKM0();
    MFMA_QUAD(1);
    __builtin_amdgcn_sched_barrier(0);
    SBAR();

    // ---- phase c (quadrant 2) ----
    if (T + 2 < NT) stage_half(Y, lds + cur + 16384, rowB0, k2, tid);
    READ_A(2);
    __builtin_amdgcn_sched_barrier(0);
    SBAR(); LGKM0();
    MFMA_QUAD(2);
    __builtin_amdgcn_sched_barrier(0);
    SBAR();

    // ---- phase d (quadrant 3) ----
    if (T + 2 < NT) stage_half(Y, lds + cur + 24576, rowB0 + 128, k2, tid);
    READ_A(3);
    __builtin_amdgcn_sched_barrier(0);
    SBAR(); LGKM0();
    MFMA_QUAD(3);
    __builtin_amdgcn_sched_barrier(0);
    if (T < NT - 2) { VMCNT(4); } else { VMCNT(0); }  // K(T+1) complete
    SBAR();
  }

  // ---- straight write first: stores drain under the mirror's LDS work ----
  const int crow0 = rowA0 + wr * 128;
  const int ccol  = rowB0 + wn * 64 + l15;
  #pragma unroll
  for (int m = 0; m < 8; ++m)
    #pragma unroll
    for (int n = 0; n < 4; ++n)
      #pragma unroll
      for (int r = 0; r < 4; ++r) {
        const int row = crow0 + m * 16 + lh * 4 + r;
        C[(size_t)row * NROWS + ccol + n * 16] = acc[m][n][r] * 0.25f;
      }

  // ---- mirror write via LDS transpose (off-diagonal tiles only) ----
  if (by != bx) {
    float (*tr)[257] = (float(*)[257])lds;   // 64 x 257 f32
    #pragma unroll
    for (int s = 0; s < 4; ++s) {
      if (s > 0) SBAR();                 // slice s-1 readers done
      if (wn == s) {
        #pragma unroll
        for (int m = 0; m < 8; ++m)
          #pragma unroll
          for (int n = 0; n < 4; ++n)
            #pragma unroll
            for (int r = 0; r < 4; ++r) {
              const int cl = n * 16 + l15;                      // 0..63
              const int rl = wr * 128 + m * 16 + lh * 4 + r;    // 0..255
              tr[cl][rl] = acc[m][n][r];
            }
        LGKM0();                          // my ds_writes visible
      }
      SBAR();
      #pragma unroll
      for (int q = 0; q < 8; ++q) {
        const int idx = q * 512 + tid;        // 0..4095
        const int ii  = idx >> 6;             // 0..63
        const int jj  = (idx & 63) * 4;       // 0..252
        f32x4 v = { tr[ii][jj] * 0.25f, tr[ii][jj + 1] * 0.25f,
                    tr[ii][jj + 2] * 0.25f, tr[ii][jj + 3] * 0.25f };
        *(f32x4*)(C + (size_t)(rowB0 + s * 64 + ii) * NROWS + rowA0 + jj) = v;
      }
    }
  }
#undef READ_A
#undef MFMA_QUAD
}

// --------------------------------------------------------------------------
// Kernel 2: persistent C = Y*Y^T / 4.  256 blocks (1/CU at 128 KiB LDS),
// each loops over a dynamic work queue of 528 tile-jobs:
//   pos 0..495   : strict-lower off-diagonal tiles (expensive — grabbed first)
//   pos 496..527 : diagonal tiles (cheap, no mirror — short tail jobs, LPT)
// ctr != nullptr: dynamic atomicAdd stealing (device-scope, self-balancing).
// ctr == nullptr: static fallback pos = bid + r*NPERS over the same ordering.
// Output is identical regardless of which block computes which tile.
// --------------------------------------------------------------------------
__global__ __launch_bounds__(512, 2) void gemm_yyt(const unsigned short* __restrict__ Y,
                                                   float* __restrict__ C,
                                                   unsigned int* __restrict__ ctr) {
  __shared__ __attribute__((aligned(16))) unsigned short lds[65536];  // 128 KiB
  __shared__ int pos_sh;

  const int tid  = threadIdx.x;
  const int lane = tid & 63;
  const int wv   = tid >> 6;
  const int wr   = wv >> 2;       // 0..1  (M)
  const int wn   = wv & 3;        // 0..3  (N)
  const int l15  = lane & 15;
  const int lh   = lane >> 4;     // 0..3

  int r = 0;
  for (;;) {
    if (tid == 0) {
      pos_sh = ctr ? (int)atomicAdd(ctr, 1u) : (int)blockIdx.x + r * NPERS;
    }
    __syncthreads();               // broadcast pos AND fence lds reuse
    const int pos = pos_sh;
    ++r;
    if (pos >= NTILES) break;

    int by, bx;
    if (pos < NOFF) {
      int b = (int)((sqrtf(8.0f * (float)pos + 1.0f) + 1.0f) * 0.5f);
      while (b * (b - 1) / 2 > pos) --b;
      while ((b + 1) * b / 2 <= pos) ++b;
      by = b;
      bx = pos - b * (b - 1) / 2;              // 0 <= bx < by
    } else {
      by = bx = pos - NOFF;
    }

    run_tile(Y, C, lds, by, bx, tid, lane, wr, wn, l15, lh);
    __syncthreads();               // all waves done with lds before next stage
  }
}

// --------------------------------------------------------------------------
extern "C" void kernel_launch(void* const* d_in, const int* in_sizes, int n_in,
                              void* d_out, int out_size, void* d_ws, size_t ws_size,
                              hipStream_t stream) {
  (void)in_sizes; (void)n_in; (void)out_size;
  const float* x  = (const float*)d_in[0];   // [8192, 256] f32
  const float* av = (const float*)d_in[1];   // [4, 256] f32
  float* C = (float*)d_out;                  // [8192, 8192] f32
  unsigned short* Y = (unsigned short*)d_ws; // [8192, 1024] bf16 scratch (16 MiB)

  const size_t ybytes = (size_t)NROWS * KTOT * sizeof(unsigned short);
  unsigned int* ctr = nullptr;
  if (ws_size >= ybytes + sizeof(unsigned int)) {
    ctr = (unsigned int*)((char*)d_ws + ybytes);
    hipMemsetAsync(ctr, 0, sizeof(unsigned int), stream);
  }

  prep_y<<<NROWS, 256, 0, stream>>>(x, av, Y);
  gemm_yyt<<<NPERS, 512, 0, stream>>>(Y, C, ctr);
}

// Round 11
// 131.748 us; speedup vs baseline: 1.3273x; 1.3273x over previous
//
#include <hip/hip_runtime.h>
#include <hip/hip_bf16.h>
#include <stdint.h>

typedef __attribute__((ext_vector_type(8))) short short8;
typedef __attribute__((ext_vector_type(4))) float f32x4;

#define NROWS  8192
#define DDIM   256
#define HHEADS 4
#define KTOT   1024            // H * D
#define BM     256
#define BN     256
#define BK     64
#define NT     (KTOT / BK)     // 16 K-tiles
#define NTB    (NROWS / BM)    // 32 tile rows
#define NOFF   (NTB * (NTB - 1) / 2)   // 496 strict-lower tiles (= 8*62)
#define NBLK   (NOFF + NTB)            // 528 blocks: off-diag first, diag tail

#define SBAR()  __builtin_amdgcn_s_barrier()
#define LGKM0() do { asm volatile("s_waitcnt lgkmcnt(0)" ::: "memory"); \
                     __builtin_amdgcn_sched_barrier(0); } while (0)
#define VMCNT(n) do { asm volatile("s_waitcnt vmcnt(" #n ")" ::: "memory"); \
                      __builtin_amdgcn_sched_barrier(0); } while (0)

__device__ __forceinline__ unsigned short f2bf(float f) {
  union { float f; uint32_t u; } v;
  v.f = f;
  uint32_t u = v.u;
  uint32_t r = (u + 0x7fffu + ((u >> 16) & 1u)) >> 16;
  return (unsigned short)r;
}

// --------------------------------------------------------------------------
// Kernel 1: Y[n, h*256+d] = bf16-normalized per-head scaled rows
// --------------------------------------------------------------------------
__global__ __launch_bounds__(256) void prep_y(const float* __restrict__ x,
                                              const float* __restrict__ av,
                                              unsigned short* __restrict__ Y) {
  __shared__ float a_sh[HHEADS][DDIM];
  __shared__ float red[4][HHEADS];

  const int t = threadIdx.x;
  #pragma unroll
  for (int h = 0; h < HHEADS; ++h) a_sh[h][t] = av[h * DDIM + t];
  __syncthreads();

  const int n = blockIdx.x;
  const float xd = x[(size_t)n * DDIM + t];

  float p[HHEADS], s[HHEADS];
  #pragma unroll
  for (int h = 0; h < HHEADS; ++h) { p[h] = a_sh[h][t] * xd; s[h] = p[h] * p[h]; }

  #pragma unroll
  for (int off = 32; off > 0; off >>= 1) {
    #pragma unroll
    for (int h = 0; h < HHEADS; ++h) s[h] += __shfl_xor(s[h], off, 64);
  }

  const int wave = t >> 6, lane = t & 63;
  if (lane == 0) {
    #pragma unroll
    for (int h = 0; h < HHEADS; ++h) red[wave][h] = s[h];
  }
  __syncthreads();

  #pragma unroll
  for (int h = 0; h < HHEADS; ++h) {
    const float sum = red[0][h] + red[1][h] + red[2][h] + red[3][h];
    const float rn = rsqrtf(fmaxf(sum, 1e-12f));
    Y[(size_t)n * KTOT + h * DDIM + t] = f2bf(p[h] * rn);
  }
}

// --------------------------------------------------------------------------
// stage one 128x64 bf16 half-tile: 2 x global_load_lds(16B) per thread.
// Linear LDS dest + inverse-swizzled global source (rule #21).
// --------------------------------------------------------------------------
__device__ __forceinline__ void stage_half(const unsigned short* __restrict__ Y,
                                           unsigned short* lds_region,
                                           int grow0, int k0, int tid) {
  #pragma unroll
  for (int i = 0; i < 2; ++i) {
    const int s    = i * 512 + tid;       // 16B slot 0..1023
    const int srow = s >> 3;              // 0..127
    const int gsl  = (s & 7) ^ (srow & 7);
    const unsigned short* gsrc =
        Y + (size_t)(grow0 + srow) * KTOT + k0 + gsl * 8;
    __builtin_amdgcn_global_load_lds(
        (const __attribute__((address_space(1))) void*)gsrc,
        (__attribute__((address_space(3))) void*)(lds_region + s * 8), 16, 0, 0);
  }
}

// --------------------------------------------------------------------------
// Kernel 2: C = Y*Y^T / 4.  ONE tile per block (fresh blocks — stores drain
// under the NEXT block's compute; a persistent loop would couple them through
// the single in-order vmcnt counter, serializing store-drain vs K-loop:
// that was round 10's regression).
//   blockIdx 0..495   : strict-lower off-diagonal tiles (XCD-swizzled)
//   blockIdx 496..527 : diagonal tiles (cheap, no mirror) — dispatch tail
// 8-phase K-loop ledger (tile T, phases a-d = output quadrants 0-3):
//   a: issue A-lo(T+1)->buf[T+1]; b: A-hi(T+1)->buf[T+1]
//   c: B-lo(T+2)->buf[T];        d: B-hi(T+2)->buf[T]; vmcnt(4)
// --------------------------------------------------------------------------
__global__ __launch_bounds__(512, 2) void gemm_yyt(const unsigned short* __restrict__ Y,
                                                   float* __restrict__ C) {
  __shared__ __attribute__((aligned(16))) unsigned short lds[65536];  // 128 KiB

  const int orig = blockIdx.x;
  int by, bx;
  if (orig < NOFF) {
    const int wg = (orig & 7) * (NOFF / 8) + (orig >> 3);   // bijective XCD swizzle
    int b = (int)((sqrtf(8.0f * (float)wg + 1.0f) + 1.0f) * 0.5f);
    while (b * (b - 1) / 2 > wg) --b;
    while ((b + 1) * b / 2 <= wg) ++b;
    by = b;
    bx = wg - b * (b - 1) / 2;                  // 0 <= bx < by
  } else {
    by = bx = orig - NOFF;                      // diagonal
  }

  const int tid  = threadIdx.x;
  const int lane = tid & 63;
  const int wv   = tid >> 6;
  const int wr   = wv >> 2;       // 0..1  (M)
  const int wn   = wv & 3;        // 0..3  (N)
  const int l15  = lane & 15;
  const int lh   = lane >> 4;     // 0..3

  const int rowA0 = by * BM;
  const int rowB0 = bx * BN;

  const int arow = wr * 128 + l15;   // local A row base
  const int brow = wn * 64 + l15;    // local B row base
  const int slA0 = (0 + lh) ^ (arow & 7), slA1 = (4 + lh) ^ (arow & 7);
  const int slB0 = (0 + lh) ^ (brow & 7), slB1 = (4 + lh) ^ (brow & 7);

  f32x4 acc[8][4];
  #pragma unroll
  for (int m = 0; m < 8; ++m)
    #pragma unroll
    for (int n = 0; n < 4; ++n) acc[m][n] = (f32x4){0.f, 0.f, 0.f, 0.f};

  // prologue: K0 all 4 halves + B halves of K1
  stage_half(Y, lds + 0,             rowA0,       0,  tid);  // A-lo(0)
  stage_half(Y, lds + 8192,          rowA0 + 128, 0,  tid);  // A-hi(0)
  stage_half(Y, lds + 16384,         rowB0,       0,  tid);  // B-lo(0)
  stage_half(Y, lds + 24576,         rowB0 + 128, 0,  tid);  // B-hi(0)
  stage_half(Y, lds + 32768 + 16384, rowB0,       64, tid);  // B-lo(1)
  stage_half(Y, lds + 32768 + 24576, rowB0 + 128, 64, tid);  // B-hi(1)
  VMCNT(4);   // K0 complete; B(1) may fly
  SBAR();

  short8 bf[4][2], af[2][2];

#define READ_A(q) do {                                                        \
    _Pragma("unroll")                                                         \
    for (int mm = 0; mm < 2; ++mm) {                                          \
      const int r_ = arow + ((q) * 2 + mm) * 16;                              \
      af[mm][0] = *(const short8*)(lds + cur + r_ * 64 + slA0 * 8);           \
      af[mm][1] = *(const short8*)(lds + cur + r_ * 64 + slA1 * 8);           \
    }                                                                         \
  } while (0)

#define MFMA_QUAD(q) do {                                                     \
    __builtin_amdgcn_s_setprio(1);                                            \
    _Pragma("unroll")                                                         \
    for (int mm = 0; mm < 2; ++mm)                                            \
      _Pragma("unroll")                                                       \
      for (int n = 0; n < 4; ++n) {                                           \
        acc[(q)*2+mm][n] = __builtin_amdgcn_mfma_f32_16x16x32_bf16(           \
            af[mm][0], bf[n][0], acc[(q)*2+mm][n], 0, 0, 0);                  \
        acc[(q)*2+mm][n] = __builtin_amdgcn_mfma_f32_16x16x32_bf16(           \
            af[mm][1], bf[n][1], acc[(q)*2+mm][n], 0, 0, 0);                  \
      }                                                                       \
    __builtin_amdgcn_s_setprio(0);                                            \
  } while (0)

  for (int T = 0; T < NT; ++T) {
    const int cur = (T & 1) << 15;
    const int nxt = ((T + 1) & 1) << 15;
    const int k1  = (T + 1) * BK;
    const int k2  = (T + 2) * BK;

    // ---- phase a (quadrant 0): B frags + A m0,m1 ----
    if (T + 1 < NT) stage_half(Y, lds + nxt, rowA0, k1, tid);        // A-lo(T+1)
    #pragma unroll
    for (int n = 0; n < 4; ++n) {
      const int r_ = brow + n * 16;
      bf[n][0] = *(const short8*)(lds + cur + 16384 + r_ * 64 + slB0 * 8);
      bf[n][1] = *(const short8*)(lds + cur + 16384 + r_ * 64 + slB1 * 8);
    }
    READ_A(0);
    __builtin_amdgcn_sched_barrier(0);
    SBAR(); LGKM0();
    MFMA_QUAD(0);
    __builtin_amdgcn_sched_barrier(0);
    SBAR();

    // ---- phase b (quadrant 1) ----
    if (T + 1 < NT) stage_half(Y, lds + nxt + 8192, rowA0 + 128, k1, tid);
    READ_A(1);
    __builtin_amdgcn_sched_barrier(0);
    SBAR(); LGKM0();
    MFMA_QUAD(1);
    __builtin_amdgcn_sched_barrier(0);
    SBAR();

    // ---- phase c (quadrant 2) ----
    if (T + 2 < NT) stage_half(Y, lds + cur + 16384, rowB0, k2, tid);
    READ_A(2);
    __builtin_amdgcn_sched_barrier(0);
    SBAR(); LGKM0();
    MFMA_QUAD(2);
    __builtin_amdgcn_sched_barrier(0);
    SBAR();

    // ---- phase d (quadrant 3) ----
    if (T + 2 < NT) stage_half(Y, lds + cur + 24576, rowB0 + 128, k2, tid);
    READ_A(3);
    __builtin_amdgcn_sched_barrier(0);
    SBAR(); LGKM0();
    MFMA_QUAD(3);
    __builtin_amdgcn_sched_barrier(0);
    if (T < NT - 2) { VMCNT(4); } else { VMCNT(0); }  // K(T+1) complete
    SBAR();
  }

  // ---- straight write first: stores drain under the mirror's LDS work ----
  const int crow0 = rowA0 + wr * 128;
  const int ccol  = rowB0 + wn * 64 + l15;
  #pragma unroll
  for (int m = 0; m < 8; ++m)
    #pragma unroll
    for (int n = 0; n < 4; ++n)
      #pragma unroll
      for (int r = 0; r < 4; ++r) {
        const int row = crow0 + m * 16 + lh * 4 + r;
        C[(size_t)row * NROWS + ccol + n * 16] = acc[m][n][r] * 0.25f;
      }

  // ---- mirror write via LDS transpose (off-diagonal tiles only) ----
  // acc[m][n][0..3] are 4 consecutive ROWS at one col => 4 consecutive rl in
  // the transposed tile => single ds_write_b128 each (32 total vs 128 b32;
  // kills round-10's 4M bank-conflict count).  tr stride 260 keeps 16B align.
  if (by != bx) {
    float (*tr)[260] = (float(*)[260])lds;   // 64 x 260 f32 = 66.6 KB
    #pragma unroll
    for (int s = 0; s < 4; ++s) {
      if (s > 0) SBAR();                 // slice s-1 readers done
      if (wn == s) {
        #pragma unroll
        for (int m = 0; m < 8; ++m)
          #pragma unroll
          for (int n = 0; n < 4; ++n) {
            const int cl  = n * 16 + l15;                    // 0..63
            const int rl0 = wr * 128 + m * 16 + lh * 4;      // 0..252, %4==0
            *(f32x4*)&tr[cl][rl0] = acc[m][n];
          }
        LGKM0();                          // my ds_writes visible
      }
      SBAR();
      #pragma unroll
      for (int q = 0; q < 8; ++q) {
        const int idx = q * 512 + tid;        // 0..4095
        const int ii  = idx >> 6;             // 0..63
        const int jj  = (idx & 63) * 4;       // 0..252
        f32x4 v = *(const f32x4*)&tr[ii][jj];
        v *= 0.25f;
        *(f32x4*)(C + (size_t)(rowB0 + s * 64 + ii) * NROWS + rowA0 + jj) = v;
      }
    }
  }
#undef READ_A
#undef MFMA_QUAD
}

// --------------------------------------------------------------------------
extern "C" void kernel_launch(void* const* d_in, const int* in_sizes, int n_in,
                              void* d_out, int out_size, void* d_ws, size_t ws_size,
                              hipStream_t stream) {
  (void)in_sizes; (void)n_in; (void)out_size; (void)ws_size;
  const float* x  = (const float*)d_in[0];   // [8192, 256] f32
  const float* av = (const float*)d_in[1];   // [4, 256] f32
  float* C = (float*)d_out;                  // [8192, 8192] f32
  unsigned short* Y = (unsigned short*)d_ws; // [8192, 1024] bf16 scratch (16 MiB)

  prep_y<<<NROWS, 256, 0, stream>>>(x, av, Y);
  gemm_yyt<<<NBLK, 512, 0, stream>>>(Y, C);
}

// Round 12
// 127.065 us; speedup vs baseline: 1.3762x; 1.0369x over previous
//
#include <hip/hip_runtime.h>
#include <hip/hip_bf16.h>
#include <stdint.h>

typedef __attribute__((ext_vector_type(8))) short short8;
typedef __attribute__((ext_vector_type(4))) float f32x4;

#define NROWS  8192
#define DDIM   256
#define HHEADS 4
#define KTOT   1024
#define BM     256
#define BN     128
#define BK     32
#define NT     (KTOT / BK)        // 32 K-tiles
#define NRB    (NROWS / BM)       // 32 row-blocks
#define NJOBS  (NRB * NRB + NRB)  // sum(2i+2) = 1056 = 8*132
#define BUFE   12288              // elems per K-tile buf: A 8192 + B 4096 (24 KB)

#define SBAR()  __builtin_amdgcn_s_barrier()
#define LGKM0() do { asm volatile("s_waitcnt lgkmcnt(0)" ::: "memory"); \
                     __builtin_amdgcn_sched_barrier(0); } while (0)
#define VMCNT(n) do { asm volatile("s_waitcnt vmcnt(" #n ")" ::: "memory"); \
                      __builtin_amdgcn_sched_barrier(0); } while (0)

__device__ __forceinline__ unsigned short f2bf(float f) {
  union { float f; uint32_t u; } v;
  v.f = f;
  uint32_t u = v.u;
  uint32_t r = (u + 0x7fffu + ((u >> 16) & 1u)) >> 16;
  return (unsigned short)r;
}

// --------------------------------------------------------------------------
// Kernel 1: Y[n, h*256+d] = bf16-normalized per-head scaled rows
// --------------------------------------------------------------------------
__global__ __launch_bounds__(256) void prep_y(const float* __restrict__ x,
                                              const float* __restrict__ av,
                                              unsigned short* __restrict__ Y) {
  __shared__ float a_sh[HHEADS][DDIM];
  __shared__ float red[4][HHEADS];

  const int t = threadIdx.x;
  #pragma unroll
  for (int h = 0; h < HHEADS; ++h) a_sh[h][t] = av[h * DDIM + t];
  __syncthreads();

  const int n = blockIdx.x;
  const float xd = x[(size_t)n * DDIM + t];

  float p[HHEADS], s[HHEADS];
  #pragma unroll
  for (int h = 0; h < HHEADS; ++h) { p[h] = a_sh[h][t] * xd; s[h] = p[h] * p[h]; }

  #pragma unroll
  for (int off = 32; off > 0; off >>= 1) {
    #pragma unroll
    for (int h = 0; h < HHEADS; ++h) s[h] += __shfl_xor(s[h], off, 64);
  }

  const int wave = t >> 6, lane = t & 63;
  if (lane == 0) {
    #pragma unroll
    for (int h = 0; h < HHEADS; ++h) red[wave][h] = s[h];
  }
  __syncthreads();

  #pragma unroll
  for (int h = 0; h < HHEADS; ++h) {
    const float sum = red[0][h] + red[1][h] + red[2][h] + red[3][h];
    const float rn = rsqrtf(fmaxf(sum, 1e-12f));
    Y[(size_t)n * KTOT + h * DDIM + t] = f2bf(p[h] * rn);
  }
}

// --------------------------------------------------------------------------
// stage one 24 KB K-tile (A 256x32 + B 128x32 bf16): 3 global_load_lds(16B)
// per thread.  Linear LDS dest; add-rotate swizzle slot'=(slot+(row>>1))&3
// applied on the GLOBAL source (rule #21): LDS slot sl of row r holds global
// chunk (sl - (r>>1)) & 3, so the ds_read at slot (lh+(row>>1))&3 yields
// chunk lh.  Linear layout would be an 8-way bank conflict (64 B rows);
// this pattern is 2-way (free, m136).
// --------------------------------------------------------------------------
__device__ __forceinline__ void stage_tile(const unsigned short* __restrict__ Y,
                                           unsigned short* buf,
                                           int rowA0, int rowB0, int k0, int tid) {
  #pragma unroll
  for (int i = 0; i < 2; ++i) {                    // A region: 1024 slots
    const int s   = i * 512 + tid;
    const int r   = s >> 2;
    const int gsl = ((s & 3) + 4 - ((r >> 1) & 3)) & 3;
    const unsigned short* gsrc = Y + (size_t)(rowA0 + r) * KTOT + k0 + gsl * 8;
    __builtin_amdgcn_global_load_lds(
        (const __attribute__((address_space(1))) void*)gsrc,
        (__attribute__((address_space(3))) void*)(buf + s * 8), 16, 0, 0);
  }
  {                                                // B region: 512 slots
    const int s   = tid;
    const int r   = s >> 2;
    const int gsl = ((s & 3) + 4 - ((r >> 1) & 3)) & 3;
    const unsigned short* gsrc = Y + (size_t)(rowB0 + r) * KTOT + k0 + gsl * 8;
    __builtin_amdgcn_global_load_lds(
        (const __attribute__((address_space(1))) void*)gsrc,
        (__attribute__((address_space(3))) void*)(buf + 8192 + s * 8), 16, 0, 0);
  }
}

// --------------------------------------------------------------------------
// Kernel 2: C = Y*Y^T / 4 on 256x128 tiles, tri-buffered BK=32 K-loop,
// 2 blocks/CU co-resident (LDS 72 KB, <=128 VGPR via __launch_bounds__).
// Job (i,j): row-block i (256 rows), col-block j (128 cols), j < 2i+2.
// Straddlers (j >= 2i) skip the mirror (their transpose region is covered
// by straight writes; all overlapping writes carry identical values).
// Ledger per K-tile T: issue stage(T+2 -> buf[(T+2)%3]) (3 loads);
// ds_read frags from buf[T%3]; lgkmcnt(0); 16 MFMA; vmcnt(3) (T+1 landed,
// T+2's 3 loads stay in flight); s_barrier.  Single barrier per K-tile is
// safe: every wave's reads of buf[(T+2)%3]'s old data completed (lgkm0)
// before the end-of-(T-1) barrier that precedes the overwrite.
// --------------------------------------------------------------------------
__global__ __launch_bounds__(512, 4) void gemm_yyt(const unsigned short* __restrict__ Y,
                                                   float* __restrict__ C) {
  __shared__ __attribute__((aligned(16))) unsigned short lds[3 * BUFE];  // 73.7 KB

  // bijective XCD swizzle: 1056 = 8 * 132
  const int orig = blockIdx.x;
  const int wg   = (orig & 7) * (NJOBS / 8) + (orig >> 3);

  // decode: jobs before row-block i = i*i + i ; j in [0, 2i+2)
  int i = (int)((sqrtf(4.0f * (float)wg + 1.0f) - 1.0f) * 0.5f);
  while ((i + 1) * (i + 1) + (i + 1) <= wg) ++i;
  while (i * i + i > wg) --i;
  const int j = wg - i * i - i;

  const int rowA0 = i * BM;          // C row block (256)
  const int rowB0 = j * BN;          // C col block (128)
  const bool mirror = (j < 2 * i);

  const int tid  = threadIdx.x;
  const int lane = tid & 63;
  const int wv   = tid >> 6;
  const int wr   = wv >> 1;          // 0..3 (M)
  const int wn   = wv & 1;           // 0..1 (N)
  const int l15  = lane & 15;
  const int lh   = lane >> 4;        // 0..3

  f32x4 acc[4][4];
  #pragma unroll
  for (int m = 0; m < 4; ++m)
    #pragma unroll
    for (int n = 0; n < 4; ++n) acc[m][n] = (f32x4){0.f, 0.f, 0.f, 0.f};

  // prologue: stage K-tiles 0 and 1
  stage_tile(Y, lds + 0,    rowA0, rowB0, 0,  tid);
  stage_tile(Y, lds + BUFE, rowA0, rowB0, BK, tid);
  VMCNT(3);    // tile 0 landed; tile 1's 3 loads may fly
  SBAR();
  __builtin_amdgcn_sched_barrier(0);

  int cur = 0;
  int nx2 = 2 * BUFE;
  short8 af[4], bf[4];

  for (int T = 0; T < NT; ++T) {
    if (T + 2 < NT) stage_tile(Y, lds + nx2, rowA0, rowB0, (T + 2) * BK, tid);

    #pragma unroll
    for (int m = 0; m < 4; ++m) {
      const int r_ = wr * 64 + m * 16 + l15;
      const int sl = (lh + ((r_ >> 1) & 3)) & 3;
      af[m] = *(const short8*)(lds + cur + r_ * 32 + sl * 8);
    }
    #pragma unroll
    for (int n = 0; n < 4; ++n) {
      const int r_ = wn * 64 + n * 16 + l15;
      const int sl = (lh + ((r_ >> 1) & 3)) & 3;
      bf[n] = *(const short8*)(lds + cur + 8192 + r_ * 32 + sl * 8);
    }
    __builtin_amdgcn_sched_barrier(0);
    LGKM0();

    __builtin_amdgcn_s_setprio(1);
    #pragma unroll
    for (int m = 0; m < 4; ++m)
      #pragma unroll
      for (int n = 0; n < 4; ++n)
        acc[m][n] = __builtin_amdgcn_mfma_f32_16x16x32_bf16(
            af[m], bf[n], acc[m][n], 0, 0, 0);
    __builtin_amdgcn_s_setprio(0);
    __builtin_amdgcn_sched_barrier(0);

    if (T < NT - 2)       { VMCNT(3); }   // T+1 landed; T+2 in flight
    else if (T == NT - 2) { VMCNT(0); }   // last prefetch (T+1) landed
    SBAR();

    cur += BUFE; if (cur == 3 * BUFE) cur = 0;
    nx2 += BUFE; if (nx2 == 3 * BUFE) nx2 = 0;
  }

  // ---- straight write: stores drain under the mirror's LDS work / exit ----
  const int crow0 = rowA0 + wr * 64;
  const int ccol  = rowB0 + wn * 64 + l15;
  #pragma unroll
  for (int m = 0; m < 4; ++m)
    #pragma unroll
    for (int n = 0; n < 4; ++n)
      #pragma unroll
      for (int r = 0; r < 4; ++r) {
        const int row = crow0 + m * 16 + lh * 4 + r;
        C[(size_t)row * NROWS + ccol + n * 16] = acc[m][n][r] * 0.25f;
      }

  // ---- mirror write via LDS transpose: C[col][row] = tile[row][col] ----
  if (mirror) {
    float (*tr)[260] = (float(*)[260])lds;   // 32 x 260 f32 = 33.3 KB
    #pragma unroll
    for (int s = 0; s < 4; ++s) {            // col slices of 32
      if (s > 0) SBAR();                     // previous slice readers done
      if (wn == (s >> 1)) {
        const int ns = 2 * (s & 1);
        #pragma unroll
        for (int nn = 0; nn < 2; ++nn)
          #pragma unroll
          for (int m = 0; m < 4; ++m) {
            const int cl  = nn * 16 + l15;                 // 0..31
            const int rl0 = wr * 64 + m * 16 + lh * 4;     // 0..252, %4==0
            *(f32x4*)&tr[cl][rl0] = acc[m][ns + nn];
          }
        LGKM0();                             // my ds_writes visible
      }
      SBAR();
      #pragma unroll
      for (int q = 0; q < 4; ++q) {
        const int idx = q * 512 + tid;       // 0..2047
        const int ii  = idx >> 6;            // 0..31
        const int jj  = (idx & 63) * 4;      // 0..252
        f32x4 v = *(const f32x4*)&tr[ii][jj];
        v *= 0.25f;
        *(f32x4*)(C + (size_t)(rowB0 + s * 32 + ii) * NROWS + rowA0 + jj) = v;
      }
    }
  }
}

// --------------------------------------------------------------------------
extern "C" void kernel_launch(void* const* d_in, const int* in_sizes, int n_in,
                              void* d_out, int out_size, void* d_ws, size_t ws_size,
                              hipStream_t stream) {
  (void)in_sizes; (void)n_in; (void)out_size; (void)ws_size;
  const float* x  = (const float*)d_in[0];   // [8192, 256] f32
  const float* av = (const float*)d_in[1];   // [4, 256] f32
  float* C = (float*)d_out;                  // [8192, 8192] f32
  unsigned short* Y = (unsigned short*)d_ws; // [8192, 1024] bf16 scratch (16 MiB)

  prep_y<<<NROWS, 256, 0, stream>>>(x, av, Y);
  gemm_yyt<<<NJOBS, 512, 0, stream>>>(Y, C);
}